// Round 12
// baseline (237.584 us; speedup 1.0000x reference)
//
#include <hip/hip_runtime.h>

#define B_SZ 32768
#define K_SZ 10
#define NK   (B_SZ * K_SZ)
#define D_SZ 128
#define L_SZ 100
#define H_SZ 512

typedef float v4f __attribute__((ext_vector_type(4)));

// Kernel 1: one THREAD per (b,k). All 512 hidden units computed in-lane;
// W1/b1/W2 are read with wave-uniform indices (loop induction only) ->
// compiler emits s_load, weights live in SGPRs, broadcast to all lanes.
// No cross-lane ops, no per-lane weight traffic, no butterflies.
// Paired sigmoid (exact): w2a*sig(xa)+w2b*sig(xb)
//   = (w2a*(1+ub) + w2b*(1+ua)) / ((1+ua)(1+ub)),  u = exp(-x)
__global__ __launch_bounds__(256) void mlp_kernel(
    const int*   __restrict__ nodes,
    const int*   __restrict__ neighs,
    const int*   __restrict__ labels,
    const float* __restrict__ distance,
    const float* __restrict__ spectral,
    const float* __restrict__ freq,
    const float* __restrict__ dist_e,
    const float* __restrict__ W1,
    const float* __restrict__ b1,
    const float* __restrict__ W2,
    const float* __restrict__ b2,
    float*       __restrict__ wout)
{
    const unsigned id = blockIdx.x * 256u + threadIdx.x;   // flat (b,k)
    const unsigned b  = id / 10u;                          // magic-mul div

    const int   nb = neighs[id];
    const float f0 = freq[id];
    const float f1 = dist_e[id];
    const int   li = labels[nodes[b]];
    const float f2 = distance[li * L_SZ + labels[nb]];
    const float f3 = spectral[nb];

    float acc = 0.f;
#pragma unroll 4
    for (int p = 0; p < H_SZ / 2; ++p) {
        const int ha = 2 * p, hb = 2 * p + 1;
        // bias added last: keeps every FMA at <=1 SGPR operand
        const float xa = fmaf(W1[4*ha+0], f0, fmaf(W1[4*ha+1], f1,
                         fmaf(W1[4*ha+2], f2, W1[4*ha+3] * f3))) + b1[ha];
        const float xb = fmaf(W1[4*hb+0], f0, fmaf(W1[4*hb+1], f1,
                         fmaf(W1[4*hb+2], f2, W1[4*hb+3] * f3))) + b1[hb];
        const float ua = __expf(-xa), ub = __expf(-xb);
        const float ta = 1.f + ua,    tb = 1.f + ub;
        const float num = fmaf(W2[ha], tb, W2[hb] * ta);
        const float den = ta * tb;
        acc = fmaf(num, __builtin_amdgcn_rcpf(den), acc);
    }
    const float imp = __builtin_amdgcn_rcpf(1.f + __expf(-(acc + b2[0])));
    wout[id] = imp * 0.1f;   // / K
}

// Kernel 2: weighted gather-sum. 2 batch rows per wave (32 lanes each,
// float4 per lane = 512B per row, coalesced). nb/w read via wave-uniform
// s_load (both rows), selected per half-wave with cndmask. Embed rows are
// L3-resident (102 MB table) -> L3-BW-bound.
__global__ __launch_bounds__(256) void gather_kernel(
    const int*   __restrict__ neighs,
    const float* __restrict__ embed,
    const float* __restrict__ w,
    float*       __restrict__ out)
{
    const int tid  = blockIdx.x * 256 + (int)threadIdx.x;
    const int wv   = __builtin_amdgcn_readfirstlane(tid >> 6);  // uniform
    const int lane = threadIdx.x & 63;
    const int half = lane >> 5;
    const int l    = lane & 31;
    const int bA = wv * 2, bB = wv * 2 + 1;

    v4f a = {0.f, 0.f, 0.f, 0.f};
#pragma unroll
    for (int k = 0; k < K_SZ; ++k) {
        const int   n0 = neighs[bA * K_SZ + k];   // s_load (uniform)
        const int   n1 = neighs[bB * K_SZ + k];
        const float w0 = w[bA * K_SZ + k];
        const float w1 = w[bB * K_SZ + k];
        const int   n  = half ? n1 : n0;          // cndmask
        const float ww = half ? w1 : w0;
        const v4f   e  = ((const v4f*)(embed + (size_t)n * D_SZ))[l];
        a.x = fmaf(ww, e.x, a.x);
        a.y = fmaf(ww, e.y, a.y);
        a.z = fmaf(ww, e.z, a.z);
        a.w = fmaf(ww, e.w, a.w);
    }
    const int b = half ? bB : bA;
    __builtin_nontemporal_store(a, (v4f*)(out + (size_t)b * D_SZ) + l);
}

extern "C" void kernel_launch(void* const* d_in, const int* in_sizes, int n_in,
                              void* d_out, int out_size, void* d_ws, size_t ws_size,
                              hipStream_t stream) {
    const int*   nodes    = (const int*)  d_in[0];
    const int*   neighs   = (const int*)  d_in[1];
    const float* embed    = (const float*)d_in[2];
    const int*   labels   = (const int*)  d_in[3];
    const float* distance = (const float*)d_in[4];
    const float* spectral = (const float*)d_in[5];
    const float* freq     = (const float*)d_in[6];
    const float* dist_e   = (const float*)d_in[7];
    const float* W1       = (const float*)d_in[8];
    const float* b1       = (const float*)d_in[9];
    const float* W2       = (const float*)d_in[10];
    const float* b2       = (const float*)d_in[11];
    float* out  = (float*)d_out;
    float* wbuf = (float*)d_ws;          // NK floats = 1.31 MB, overwritten fully

    // K1: 327,680 threads = 1280 blocks (exact)
    mlp_kernel<<<NK / 256, 256, 0, stream>>>(
        nodes, neighs, labels, distance, spectral,
        freq, dist_e, W1, b1, W2, b2, wbuf);

    // K2: 2 b per wave -> 16,384 waves = 4096 blocks (exact)
    gather_kernel<<<(B_SZ / 2 * 64) / 256, 256, 0, stream>>>(
        neighs, embed, wbuf, out);
}

// Round 13
// 227.132 us; speedup vs baseline: 1.0460x; 1.0460x over previous
//
#include <hip/hip_runtime.h>

#define B_SZ 32768
#define K_SZ 10
#define D_SZ 128
#define L_SZ 100
#define BPW  4                 // batch elements per wave

typedef float v2f __attribute__((ext_vector_type(2)));
typedef float v4f __attribute__((ext_vector_type(4)));

#if __has_builtin(__builtin_amdgcn_exp2f)
#define EXP2(x) __builtin_amdgcn_exp2f(x)
#else
#define EXP2(x) __expf((x) * 0.69314718055994531f)   // exp(x*ln2) == 2^x
#endif
#define RCP(x) __builtin_amdgcn_rcpf(x)

// Fused kernel, one wave per 4 batch elements.
// Lane l owns hidden units h = l + 64*i, i=0..7; weights preloaded ONCE per
// wave into VGPRs, pre-scaled by -log2(e) so sigmoid uses exp2 directly, and
// PINNED with empty asm so the compiler cannot re-sink/reload them per
// iteration (round-12 lesson: VGPR=12 => compiler streamed weights via SGPR).
// Per b: neighbor/feature loads are wave-uniform (b uniform from wave id) ->
// s_loads; embed gathers issued EARLY (addresses known up front) so their
// ~HBM latency hides under ~2500 cycles of MLP math; VMEM gather stream
// overlaps VALU/TRANS across the 4-b loop and across resident waves.
__global__ __launch_bounds__(256) void agg_fused(
    const int*   __restrict__ nodes,
    const int*   __restrict__ neighs,
    const float* __restrict__ embed,
    const int*   __restrict__ labels,
    const float* __restrict__ distance,
    const float* __restrict__ spectral,
    const float* __restrict__ freq,
    const float* __restrict__ dist_e,
    const float* __restrict__ W1,
    const float* __restrict__ b1,
    const float* __restrict__ W2,
    const float* __restrict__ b2,
    float*       __restrict__ out)
{
    const int lane = threadIdx.x & 63;
    const int wv = __builtin_amdgcn_readfirstlane(
        (blockIdx.x * 256 + (int)threadIdx.x) >> 6);

    // ---- per-lane weight preload (8 hidden units), folded for exp2 ----
    const float NL2E = -1.44269504088896f;   // -log2(e)
    v4f   w1s[8];
    float b1s[8], w2r[8];
#pragma unroll
    for (int i = 0; i < 8; ++i) {
        const int h = lane + 64 * i;
        w1s[i] = ((const v4f*)W1)[h] * NL2E;
        b1s[i] = b1[h] * NL2E;
        w2r[i] = W2[h];
    }
#pragma unroll
    for (int i = 0; i < 8; ++i)
        asm volatile("" : "+v"(w1s[i]), "+v"(b1s[i]), "+v"(w2r[i]));
    const float b2s = b2[0] * NL2E;

    for (int bi = 0; bi < BPW; ++bi) {
        const int b = wv * BPW + bi;        // wave-uniform

        // neighbor indices (contiguous s_load), then kick off embed gathers
        int nb[K_SZ];
#pragma unroll
        for (int k = 0; k < K_SZ; ++k) nb[k] = neighs[b * K_SZ + k];

        v2f e[K_SZ];
#pragma unroll
        for (int k = 0; k < K_SZ; ++k)
            e[k] = ((const v2f*)(embed + (size_t)nb[k] * D_SZ))[lane];

        // wave-uniform scalar features
        const int li = labels[nodes[b]];
        const float* __restrict__ distRow = distance + li * L_SZ;
        float f0[K_SZ], f1[K_SZ], f2[K_SZ], f3[K_SZ];
#pragma unroll
        for (int k = 0; k < K_SZ; ++k) {
            f0[k] = freq[b * K_SZ + k];
            f1[k] = dist_e[b * K_SZ + k];
        }
        int labj[K_SZ];
#pragma unroll
        for (int k = 0; k < K_SZ; ++k) labj[k] = labels[nb[k]];
#pragma unroll
        for (int k = 0; k < K_SZ; ++k) {
            f2[k] = distRow[labj[k]];
            f3[k] = spectral[nb[k]];
        }

        // MLP partials, all k (paired sigmoid: 1 rcp / 2 hidden units;
        // x pre-scaled so u = exp2(x') = e^{-x}):
        //   w2a*sig(xa)+w2b*sig(xb) = (w2a*(1+ub)+w2b*(1+ua))/((1+ua)(1+ub))
        float part[K_SZ];
#pragma unroll
        for (int k = 0; k < K_SZ; ++k) {
            float p = 0.f;
#pragma unroll
            for (int j = 0; j < 4; ++j) {
                const v4f   wa = w1s[2*j],   wb = w1s[2*j+1];
                const float xa = fmaf(wa.x, f0[k], fmaf(wa.y, f1[k],
                                 fmaf(wa.z, f2[k], fmaf(wa.w, f3[k], b1s[2*j]))));
                const float xb = fmaf(wb.x, f0[k], fmaf(wb.y, f1[k],
                                 fmaf(wb.z, f2[k], fmaf(wb.w, f3[k], b1s[2*j+1]))));
                const float ua = EXP2(xa), ub = EXP2(xb);
                const float ta = 1.f + ua,  tb = 1.f + ub;
                const float num = fmaf(w2r[2*j], tb, w2r[2*j+1] * ta);
                p = fmaf(num, RCP(ta * tb), p);
            }
            part[k] = p;
        }

        // 10 independent 64-lane butterflies (ILP overlaps the 6 stages)
#pragma unroll
        for (int off = 32; off > 0; off >>= 1) {
#pragma unroll
            for (int k = 0; k < K_SZ; ++k)
                part[k] += __shfl_xor(part[k], off, 64);
        }

        // final sigmoid + weighted accumulate of prefetched embed rows
        float acc0 = 0.f, acc1 = 0.f;
#pragma unroll
        for (int k = 0; k < K_SZ; ++k) {
            const float imp = RCP(1.f + EXP2(fmaf(part[k], NL2E, b2s)));
            const float w   = imp * 0.1f;    // 1/K
            acc0 = fmaf(w, e[k].x, acc0);
            acc1 = fmaf(w, e[k].y, acc1);
        }
        v2f r; r.x = acc0; r.y = acc1;
        __builtin_nontemporal_store(r, (v2f*)(out + (size_t)b * D_SZ) + lane);
    }
}

extern "C" void kernel_launch(void* const* d_in, const int* in_sizes, int n_in,
                              void* d_out, int out_size, void* d_ws, size_t ws_size,
                              hipStream_t stream) {
    const int*   nodes    = (const int*)  d_in[0];
    const int*   neighs   = (const int*)  d_in[1];
    const float* embed    = (const float*)d_in[2];
    const int*   labels   = (const int*)  d_in[3];
    const float* distance = (const float*)d_in[4];
    const float* spectral = (const float*)d_in[5];
    const float* freq     = (const float*)d_in[6];
    const float* dist_e   = (const float*)d_in[7];
    const float* W1       = (const float*)d_in[8];
    const float* b1       = (const float*)d_in[9];
    const float* W2       = (const float*)d_in[10];
    const float* b2       = (const float*)d_in[11];
    float* out = (float*)d_out;

    // 4 b per wave: 8192 waves = 2048 blocks of 256 (exact; 256/XCD even)
    agg_fused<<<(B_SZ / BPW * 64) / 256, 256, 0, stream>>>(
        nodes, neighs, embed, labels, distance, spectral,
        freq, dist_e, W1, b1, W2, b2, out);
}